// Round 11
// baseline (1505.652 us; speedup 1.0000x reference)
//
#include <hip/hip_runtime.h>
#include <math.h>

// Problem: B=8, T=64, Cin=64, L=256, F=128, K=5 (SAME pad=2), fp32.
// MFMA per (t,layer): GEMM M=512 (rows r=4f+g), N=2048 (b,l), K=5*Ctot.
// fp32 as bf16x2 (AhBh+AlBh+AhBl, fp32 acc).
// R11: R10 resubmitted verbatim (R10 bench died in container acquisition,
// not in the kernel). Ntile128 + 4 waves/SIMD deconfound: R8 (Ntile64,
// 4w/SIMD) 1525 and R9 (Ntile128, 2w/SIMD) 1427 are within noise ->
// traffic and TLP changes canceled. Keep R9's halved weight traffic AND
// R8's TLP: 1024-thread blocks, 1 block/CU, 16 waves = 4 K-quarters x
// 4 N-quarters (32 cols), acc[4][2] = R8's proven 128-VGPR register
// shape (no spill). Reduction scratch 16x8x64 float4 = 128KB aliases the
// 137KB staging tile. Grid 256 = 128 L1(t-1) + 128 L0(t) concurrent
// halves, 65 launches, full ws_init (R8's repeat-call fix). If flat vs
// R9 -> launch-floor confirmed; next lever is the launch graph.
#define B_SZ 8
#define T_SZ 64
#define CIN 64
#define L_LEN 256
#define F_CH 128
#define K_W 5
#define S_BFL (B_SZ * F_CH * L_LEN)   // 262144

typedef short bf16x8 __attribute__((ext_vector_type(8)));
typedef float f32x4  __attribute__((ext_vector_type(4)));
typedef unsigned int  uint_t;
typedef unsigned short ushort_t;

__device__ __forceinline__ float sigmoid_f(float x) {
    return 1.0f / (1.0f + __expf(-x));
}
__device__ __forceinline__ float tanh_f(float x) {
    float a = fabsf(x);
    float e = __expf(-2.0f * a);
    float t = (1.0f - e) / (1.0f + e);
    return copysignf(t, x);
}
__device__ __forceinline__ ushort_t bf16rne(float f) {
    uint_t u = __float_as_uint(f);
    uint_t r = (u + 0x7FFFu + ((u >> 16) & 1u)) >> 16;
    return (ushort_t)r;
}
// packed word = hi_bf16 | lo_bf16 << 16
__device__ __forceinline__ uint_t pack_f32(float v) {
    ushort_t h = bf16rne(v);
    float hf = __uint_as_float(((uint_t)h) << 16);
    ushort_t l = bf16rne(v - hf);
    return (uint_t)h | (((uint_t)l) << 16);
}

union FragU { uint4 q; bf16x8 v; f32x4 f; float4 f4; };

// ---- Pre-pass: weights -> bf16x2 in A-fragment order ----------------------
// A'[kk=tap*KS+ks][koct][512 rows r=4f+g][8 bf16], hi and lo arrays.
template<int CTOT>
__global__ __launch_bounds__(256)
void convert_w(const float* __restrict__ W, ushort_t* __restrict__ Ahi,
               ushort_t* __restrict__ Alo)
{
    constexpr int KS = CTOT / 32;
    const int idx = blockIdx.x * 256 + threadIdx.x;
    if (idx >= 5 * KS * 4 * 512) return;
    const int r    = idx & 511;
    int rest       = idx >> 9;
    const int koct = rest & 3;  rest >>= 2;
    const int ks   = rest % KS;
    const int tap  = rest / KS;
    const int f = r >> 2, g = r & 3;
    const int row = g * F_CH + f;
    #pragma unroll
    for (int j = 0; j < 8; ++j) {
        int c = ks * 32 + koct * 8 + j;
        float w = W[(row * CTOT + c) * K_W + tap];
        ushort_t h = bf16rne(w);
        ushort_t l = bf16rne(w - __uint_as_float(((uint_t)h) << 16));
        Ahi[idx * 8 + j] = h;
        Alo[idx * 8 + j] = l;
    }
}

__global__ __launch_bounds__(256)
void remap_bias(const float* __restrict__ b0, const float* __restrict__ b1,
                float* __restrict__ br0, float* __restrict__ br1)
{
    int r = blockIdx.x * 256 + threadIdx.x;
    if (r < 512)       br0[r] = b0[(r & 3) * F_CH + (r >> 2)];
    else { r -= 512;   br1[r] = b1[(r & 3) * F_CH + (r >> 2)]; }
}

// Initialize EVERY read-before-write workspace location each call:
// both parities of hp0/hp1, and the c work buffers.
__global__ __launch_bounds__(256)
void ws_init(const float* __restrict__ h0, const float* __restrict__ h1,
             const float* __restrict__ c0, const float* __restrict__ c1,
             uint_t* __restrict__ hp0a, uint_t* __restrict__ hp0b,
             uint_t* __restrict__ hp1a, uint_t* __restrict__ hp1b,
             float* __restrict__ c0w, float* __restrict__ c1w)
{
    int i = blockIdx.x * 256 + threadIdx.x;
    if (i < S_BFL) {
        uint_t p0 = pack_f32(h0[i]);
        uint_t p1 = pack_f32(h1[i]);
        hp0a[i] = p0; hp0b[i] = p0;
        hp1a[i] = p1; hp1b[i] = p1;
        c0w[i] = c0[i];
        c1w[i] = c1[i];
    }
}

// ---- One layer-step for this block's (mblk, b, l0) tile -------------------
// 16 waves: w&3 = K-quarter, w>>2 = N-quarter (32 cols). Writes c/h for
// rows f in [mblk*16, mblk*16+16), columns l in [l0, l0+128), batch b.
template<int C0, int CTOT, bool IN0_F32>
__device__ void step_body(uint_t* __restrict__ sh, const int tid,
    const int mblk, const int b, const int l0,
    const float* __restrict__ in0f, int in0_b_stride,
    const uint_t* __restrict__ in0p,
    const uint_t* __restrict__ hprevp,
    const ushort_t* __restrict__ Ahi, const ushort_t* __restrict__ Alo,
    const float* __restrict__ biasr,
    const float* __restrict__ c_in, float* __restrict__ c_out,
    float* __restrict__ h_out_f32,   // null for layer 0
    uint_t* __restrict__ hp_out)
{
    constexpr int KS = CTOT / 32;
    constexpr int KK = 5 * KS;
    constexpr int STRIDE = CTOT + 4;             // words; %4==0 (b128 align)
    constexpr int LP = 132;                      // 128 cols + 4 halo rows

    // ---- Batched staging: rows lp=0..131 (l = l0+lp-2), cols = channels ---
    // Two deep rounds: issue U independent loads (clamped addresses), one
    // wait covers the whole batch of LDS writes (select-zero for halo).
    constexpr int TOT = LP * CTOT;               // 25344 / 33792
    constexpr int U = (TOT + 2047) / 2048;       // 13 / 17 -> 2 rounds
    #pragma unroll
    for (int r = 0; r < 2; ++r) {
        uint_t v[U];
        #pragma unroll
        for (int u = 0; u < U; ++u) {
            const int i = r * (1024 * U) + u * 1024 + tid;
            if (i < TOT) {
                const int c  = i / LP, lp = i - c * LP;
                const int gl = l0 + lp - 2;
                const int glc = min(max(gl, 0), L_LEN - 1);
                if (IN0_F32) {
                    const float* s = (c < C0) ? (in0f + b * in0_b_stride + c * L_LEN)
                                              : nullptr;
                    v[u] = (c < C0) ? __float_as_uint(s[glc])
                                    : hprevp[(b * F_CH + (c - C0)) * L_LEN + glc];
                } else {
                    v[u] = (c < C0) ? in0p[(b * C0 + c) * L_LEN + glc]
                                    : hprevp[(b * F_CH + (c - C0)) * L_LEN + glc];
                }
            }
        }
        #pragma unroll
        for (int u = 0; u < U; ++u) {
            const int i = r * (1024 * U) + u * 1024 + tid;
            if (i < TOT) {
                const int c  = i / LP, lp = i - c * LP;
                const int gl = l0 + lp - 2;
                uint_t w = v[u];
                if (IN0_F32 && c < C0) w = pack_f32(__uint_as_float(w));
                if (gl < 0 || gl >= L_LEN) w = 0u;
                sh[lp * STRIDE + c] = w;
            }
        }
    }
    __syncthreads();

    const int w_id = tid >> 6;      // 0..15
    const int q    = w_id & 3;      // K-quarter
    const int nh   = w_id >> 2;     // N-quarter (columns nh*32 .. nh*32+31)
    const int lane = tid & 63;
    const int l16  = lane & 15, oct = lane >> 4;
    const int mrow = mblk * 64 + l16;
    const int k_lo = (q * KK) / 4, k_hi = ((q + 1) * KK) / 4;

    f32x4 acc[4][2];
    #pragma unroll
    for (int mt = 0; mt < 4; ++mt)
        #pragma unroll
        for (int nf = 0; nf < 2; ++nf) acc[mt][nf] = (f32x4)0.0f;

    const uint4* AH4 = (const uint4*)Ahi;
    const uint4* AL4 = (const uint4*)Alo;
    const uint4* shq = (const uint4*)sh;

    uint4 A0[8], A1[8];
    auto loadA = [&](int kk, uint4* dst) {
        const int base = (kk * 4 + oct) * 512 + mrow;
        #pragma unroll
        for (int mt = 0; mt < 4; ++mt) {
            dst[2 * mt]     = AH4[base + 16 * mt];
            dst[2 * mt + 1] = AL4[base + 16 * mt];
        }
    };
    auto body = [&](int kk, uint4* A) {
        const int tap = kk / KS, ks = kk - tap * KS;
        const int cb  = ks * 8 + oct * 2;
        bf16x8 bh[2], bl[2];
        #pragma unroll
        for (int nf = 0; nf < 2; ++nf) {
            const int row = nh * 32 + nf * 16 + l16 + tap;
            const int r = row * (STRIDE / 4) + cb;
            uint4 p0 = shq[r], p1 = shq[r + 1];
            FragU H, L;
            H.q.x = __builtin_amdgcn_perm(p0.y, p0.x, 0x05040100u);
            H.q.y = __builtin_amdgcn_perm(p0.w, p0.z, 0x05040100u);
            H.q.z = __builtin_amdgcn_perm(p1.y, p1.x, 0x05040100u);
            H.q.w = __builtin_amdgcn_perm(p1.w, p1.z, 0x05040100u);
            L.q.x = __builtin_amdgcn_perm(p0.y, p0.x, 0x07060302u);
            L.q.y = __builtin_amdgcn_perm(p0.w, p0.z, 0x07060302u);
            L.q.z = __builtin_amdgcn_perm(p1.y, p1.x, 0x07060302u);
            L.q.w = __builtin_amdgcn_perm(p1.w, p1.z, 0x07060302u);
            bh[nf] = H.v; bl[nf] = L.v;
        }
        #pragma unroll
        for (int mt = 0; mt < 4; ++mt) {
            FragU TH, TL; TH.q = A[2 * mt]; TL.q = A[2 * mt + 1];
            bf16x8 ah = TH.v, al = TL.v;
            #pragma unroll
            for (int nf = 0; nf < 2; ++nf) {
                acc[mt][nf] = __builtin_amdgcn_mfma_f32_16x16x32_bf16(ah, bh[nf], acc[mt][nf], 0, 0, 0);
                acc[mt][nf] = __builtin_amdgcn_mfma_f32_16x16x32_bf16(al, bh[nf], acc[mt][nf], 0, 0, 0);
                acc[mt][nf] = __builtin_amdgcn_mfma_f32_16x16x32_bf16(ah, bl[nf], acc[mt][nf], 0, 0, 0);
            }
        }
    };

    // Software pipeline: A for kk+1 in flight while MFMAing kk.
    loadA(k_lo, A0);
    for (int kk = k_lo; kk < k_hi; kk += 2) {
        loadA(kk + 1 < k_hi ? kk + 1 : kk, A1);
        body(kk, A0);
        loadA(kk + 2 < k_hi ? kk + 2 : kk, A0);
        if (kk + 1 < k_hi) body(kk + 1, A1);
    }

    // Cross-wave K-reduction through LDS (aliases staging tile).
    __syncthreads();
    float4* scratch = (float4*)sh;                // 16*8*64 float4 = 128 KB
    #pragma unroll
    for (int mt = 0; mt < 4; ++mt)
        #pragma unroll
        for (int nf = 0; nf < 2; ++nf) {
            FragU u; u.f = acc[mt][nf];
            scratch[(w_id * 8 + mt * 2 + nf) * 64 + lane] = u.f4;
        }
    __syncthreads();

    // Wave (q, nh) finalizes mtile q of N-quarter nh:
    // rows mblk*64+q*16..+15, columns l0+nh*32 .. +31.
    #pragma unroll
    for (int nf = 0; nf < 2; ++nf) {
        float4 s = scratch[((nh * 4 + 0) * 8 + q * 2 + nf) * 64 + lane];
        #pragma unroll
        for (int w = 1; w < 4; ++w) {
            float4 p = scratch[((nh * 4 + w) * 8 + q * 2 + nf) * 64 + lane];
            s.x += p.x; s.y += p.y; s.z += p.z; s.w += p.w;
        }
        const int rbase = mblk * 64 + q * 16 + 4 * oct;     // rows rbase..+3
        const float4 b4 = *(const float4*)(biasr + rbase);
        const int f = rbase >> 2;
        float gi = sigmoid_f(s.x + b4.x);
        float gf = sigmoid_f(s.y + b4.y);
        float go = sigmoid_f(s.z + b4.z);
        float gg = tanh_f(s.w + b4.w);
        const int l   = l0 + nh * 32 + nf * 16 + l16;
        const int idx = (b * F_CH + f) * L_LEN + l;
        float cp = c_in[idx];
        float cn = gf * cp + gi * gg;
        float hn = go * tanh_f(cn);
        c_out[idx] = cn;
        if (h_out_f32) h_out_f32[idx] = hn;
        hp_out[idx] = pack_f32(hn);
    }
}

// ---- Fused concurrent-pair kernel ----------------------------------------
// Launch t (t=0..T): bx<128 -> L1(t-1) [skip at t=0],
//                    bx>=128 -> L0(t)  [skip at t=T].
// Both halves depend only on launch-(t-1) outputs (t=0 state from ws_init);
// kernel boundary is the sync + coherence point. 1 block/CU, grid 256.
struct FusedParams {
    const float* x;
    const ushort_t* Ahi0; const ushort_t* Alo0;
    const ushort_t* Ahi1; const ushort_t* Alo1;
    const float* br0; const float* br1;
    float* c0w; float* c1w;
    uint_t* hp0a; uint_t* hp0b;
    uint_t* hp1a; uint_t* hp1b;
    float* out;
};

__global__ __launch_bounds__(1024, 1)
void fused_step(FusedParams P, int t)
{
    constexpr int SH_WORDS = 132 * (256 + 4);    // 34320 w = 137.3 KB (>=RED 32768)
    __shared__ __align__(16) uint_t sh[SH_WORDS];

    const int tid  = threadIdx.x;
    const int bx   = blockIdx.x;
    const int mblk = bx & 7;                     // XCD-pinned (bx%8 round-robin)
    const int nblk = (bx & 127) >> 3;            // 0..15
    const int b    = nblk >> 1;
    const int l0   = (nblk & 1) << 7;

    if (bx < 128) {
        if (t >= 1) {
            const int tt = t - 1;
            const uint_t* hp0cur  = (tt & 1) ? P.hp0b : P.hp0a;  // L0(tt) output
            const uint_t* hp1prev = (tt & 1) ? P.hp1a : P.hp1b;
            uint_t*       hp1w    = (tt & 1) ? P.hp1b : P.hp1a;
            step_body<F_CH, 256, false>(sh, tid, mblk, b, l0,
                (const float*)nullptr, 0, hp0cur,
                hp1prev, P.Ahi1, P.Alo1, P.br1,
                P.c1w, P.c1w,
                P.out + (size_t)tt * S_BFL, hp1w);
        }
    } else {
        if (t < T_SZ) {
            const uint_t* hp0prev = (t & 1) ? P.hp0a : P.hp0b;
            uint_t*       hp0w    = (t & 1) ? P.hp0b : P.hp0a;
            step_body<CIN, 192, true>(sh, tid, mblk, b, l0,
                P.x + (size_t)t * CIN * L_LEN, T_SZ * CIN * L_LEN,
                (const uint_t*)nullptr,
                hp0prev, P.Ahi0, P.Alo0, P.br0,
                P.c0w, P.c0w,
                (float*)nullptr, hp0w);
        }
    }
}

extern "C" void kernel_launch(void* const* d_in, const int* in_sizes, int n_in,
                              void* d_out, int out_size, void* d_ws, size_t ws_size,
                              hipStream_t stream)
{
    const float* x  = (const float*)d_in[0];  // [B,T,Cin,L]
    const float* W0 = (const float*)d_in[1];  // [512,192,5]
    const float* b0 = (const float*)d_in[2];  // [512]
    const float* W1 = (const float*)d_in[3];  // [512,256,5]
    const float* b1 = (const float*)d_in[4];  // [512]
    const float* h0 = (const float*)d_in[5];  // [B,F,L]
    const float* c0 = (const float*)d_in[6];
    const float* h1 = (const float*)d_in[7];
    const float* c1 = (const float*)d_in[8];
    float* out = (float*)d_out;               // [T,B,F,L]

    const int S = S_BFL;
    float* ws  = (float*)d_ws;
    float* c0w = ws;                          // S floats
    float* c1w = ws + S;                      // S floats
    float* br0 = ws + 2 * S;                  // 512
    float* br1 = br0 + 512;
    uint_t* hp0a = (uint_t*)(ws + 2 * S + 1024);
    uint_t* hp0b = hp0a + S;
    uint_t* hp1a = hp0b + S;
    uint_t* hp1b = hp1a + S;
    ushort_t* Ahi0 = (ushort_t*)(hp1b + S);
    const int N0 = 512 * 192 * 5;             // 491520
    const int N1 = 512 * 256 * 5;             // 655360
    ushort_t* Alo0 = Ahi0 + N0;
    ushort_t* Ahi1 = Alo0 + N0;
    ushort_t* Alo1 = Ahi1 + N1;

    // Pre-pass (graph-safe, every call). ws_init covers ALL
    // read-before-write workspace state (both hp parities, c work bufs).
    convert_w<192><<<dim3(240), dim3(256), 0, stream>>>(W0, Ahi0, Alo0);
    convert_w<256><<<dim3(320), dim3(256), 0, stream>>>(W1, Ahi1, Alo1);
    remap_bias<<<dim3(4), dim3(256), 0, stream>>>(b0, b1, br0, br1);
    ws_init<<<dim3((S + 255) / 256), dim3(256), 0, stream>>>(
        h0, h1, c0, c1, hp0a, hp0b, hp1a, hp1b, c0w, c1w);

    FusedParams P;
    P.x = x;
    P.Ahi0 = Ahi0; P.Alo0 = Alo0; P.Ahi1 = Ahi1; P.Alo1 = Alo1;
    P.br0 = br0; P.br1 = br1;
    P.c0w = c0w; P.c1w = c1w;
    P.hp0a = hp0a; P.hp0b = hp0b; P.hp1a = hp1a; P.hp1b = hp1b;
    P.out = out;

    dim3 grid(256), block(1024);
    for (int t = 0; t <= T_SZ; ++t) {
        fused_step<<<grid, block, 0, stream>>>(P, t);
    }
}

// Round 12
// 1375.732 us; speedup vs baseline: 1.0944x; 1.0944x over previous
//
#include <hip/hip_runtime.h>
#include <math.h>

// Problem: B=8, T=64, Cin=64, L=256, F=128, K=5 (SAME pad=2), fp32.
// MFMA per (t,layer): GEMM M=512 (rows r=4f+g), N=2048 (b,l), K=5*Ctot.
// fp32 as bf16x2 (AhBh+AlBh+AhBl, fp32 acc).
// R12: DEEP(3) WEIGHT PREFETCH + MERGED PRE-PASS, on R9's geometry.
// R8/R9/R11 plateau at ~1430-1520 regardless of traffic/TLP/tile =>
// per-launch ~= O(7us) + W(15us/half-machine sub-step); W >> 1.9us MFMA
// floor => K-loop stalls on L3 weight refetch (L2 slices evicted by the
// per-launch activation stream; 1-body pipeline covers ~460cy < 600-900cy
// L3). Fix: 3-buffer A-ring (2-body lookahead ~930cy) with
// __launch_bounds__(512) and NO min-wave arg (R5's spill was a VGPR cap
// artifact; ~220 VGPR still gives 2 waves/SIMD). Pre-pass fused into ONE
// kernel (saves ~3 launch overheads). Everything else = R9: Ntile128,
// 512 threads, 8 waves = 4 K-quarters x 2 N-halves, concurrent-pair
// launches (bx<128 -> L1(t-1), bx>=128 -> L0(t)), full ws_init.
#define B_SZ 8
#define T_SZ 64
#define CIN 64
#define L_LEN 256
#define F_CH 128
#define K_W 5
#define S_BFL (B_SZ * F_CH * L_LEN)   // 262144

typedef short bf16x8 __attribute__((ext_vector_type(8)));
typedef float f32x4  __attribute__((ext_vector_type(4)));
typedef unsigned int  uint_t;
typedef unsigned short ushort_t;

__device__ __forceinline__ float sigmoid_f(float x) {
    return 1.0f / (1.0f + __expf(-x));
}
__device__ __forceinline__ float tanh_f(float x) {
    float a = fabsf(x);
    float e = __expf(-2.0f * a);
    float t = (1.0f - e) / (1.0f + e);
    return copysignf(t, x);
}
__device__ __forceinline__ ushort_t bf16rne(float f) {
    uint_t u = __float_as_uint(f);
    uint_t r = (u + 0x7FFFu + ((u >> 16) & 1u)) >> 16;
    return (ushort_t)r;
}
// packed word = hi_bf16 | lo_bf16 << 16
__device__ __forceinline__ uint_t pack_f32(float v) {
    ushort_t h = bf16rne(v);
    float hf = __uint_as_float(((uint_t)h) << 16);
    ushort_t l = bf16rne(v - hf);
    return (uint_t)h | (((uint_t)l) << 16);
}

union FragU { uint4 q; bf16x8 v; f32x4 f; float4 f4; };

// ---- Merged pre-pass -------------------------------------------------------
// One launch covers: convert_w<192> (240 blks), convert_w<256> (320 blks),
// remap_bias (4 blks), ws_init (1024 blks). Disjoint outputs, no ordering
// needed within the kernel.
template<int CTOT>
__device__ void convert_w_body(int idx, const float* __restrict__ W,
                               ushort_t* __restrict__ Ahi,
                               ushort_t* __restrict__ Alo)
{
    constexpr int KS = CTOT / 32;
    if (idx >= 5 * KS * 4 * 512) return;
    const int r    = idx & 511;
    int rest       = idx >> 9;
    const int koct = rest & 3;  rest >>= 2;
    const int ks   = rest % KS;
    const int tap  = rest / KS;
    const int f = r >> 2, g = r & 3;
    const int row = g * F_CH + f;
    #pragma unroll
    for (int j = 0; j < 8; ++j) {
        int c = ks * 32 + koct * 8 + j;
        float w = W[(row * CTOT + c) * K_W + tap];
        ushort_t h = bf16rne(w);
        ushort_t l = bf16rne(w - __uint_as_float(((uint_t)h) << 16));
        Ahi[idx * 8 + j] = h;
        Alo[idx * 8 + j] = l;
    }
}

__global__ __launch_bounds__(256)
void prepass(const float* __restrict__ W0, const float* __restrict__ W1,
             const float* __restrict__ b0, const float* __restrict__ b1,
             const float* __restrict__ h0, const float* __restrict__ h1,
             const float* __restrict__ c0, const float* __restrict__ c1,
             ushort_t* __restrict__ Ahi0, ushort_t* __restrict__ Alo0,
             ushort_t* __restrict__ Ahi1, ushort_t* __restrict__ Alo1,
             float* __restrict__ br0, float* __restrict__ br1,
             uint_t* __restrict__ hp0a, uint_t* __restrict__ hp0b,
             uint_t* __restrict__ hp1a, uint_t* __restrict__ hp1b,
             float* __restrict__ c0w, float* __restrict__ c1w)
{
    const int bx = blockIdx.x;
    if (bx < 240) {
        convert_w_body<192>(bx * 256 + threadIdx.x, W0, Ahi0, Alo0);
    } else if (bx < 560) {
        convert_w_body<256>((bx - 240) * 256 + threadIdx.x, W1, Ahi1, Alo1);
    } else if (bx < 564) {
        int r = (bx - 560) * 256 + threadIdx.x;
        if (r < 512)       br0[r] = b0[(r & 3) * F_CH + (r >> 2)];
        else { r -= 512;   br1[r] = b1[(r & 3) * F_CH + (r >> 2)]; }
    } else {
        int i = (bx - 564) * 256 + threadIdx.x;
        if (i < S_BFL) {
            uint_t p0 = pack_f32(h0[i]);
            uint_t p1 = pack_f32(h1[i]);
            hp0a[i] = p0; hp0b[i] = p0;
            hp1a[i] = p1; hp1b[i] = p1;
            c0w[i] = c0[i];
            c1w[i] = c1[i];
        }
    }
}

// ---- One layer-step for this block's (mblk, b, l0) tile -------------------
// 8 waves: w&3 = K-quarter, w>>2 = N-half (64 cols). Writes c/h for rows
// f in [mblk*16, mblk*16+16), columns l in [l0, l0+128), batch b.
template<int C0, int CTOT, bool IN0_F32>
__device__ void step_body(uint_t* __restrict__ sh, const int tid,
    const int mblk, const int b, const int l0,
    const float* __restrict__ in0f, int in0_b_stride,
    const uint_t* __restrict__ in0p,
    const uint_t* __restrict__ hprevp,
    const ushort_t* __restrict__ Ahi, const ushort_t* __restrict__ Alo,
    const float* __restrict__ biasr,
    const float* __restrict__ c_in, float* __restrict__ c_out,
    float* __restrict__ h_out_f32,   // null for layer 0
    uint_t* __restrict__ hp_out)
{
    constexpr int KS = CTOT / 32;
    constexpr int KK = 5 * KS;
    constexpr int STRIDE = CTOT + 4;             // words; %4==0 (b128 align)
    constexpr int LP = 132;                      // 128 cols + 4 halo rows

    // ---- Batched staging: rows lp=0..131 (l = l0+lp-2), cols = channels ---
    constexpr int TOT = LP * CTOT;               // 25344 / 33792
    constexpr int U = (TOT + 1023) / 1024;       // 25 / 33 -> 2 rounds
    #pragma unroll
    for (int r = 0; r < 2; ++r) {
        uint_t v[U];
        #pragma unroll
        for (int u = 0; u < U; ++u) {
            const int i = r * (512 * U) + u * 512 + tid;
            if (i < TOT) {
                const int c  = i / LP, lp = i - c * LP;
                const int gl = l0 + lp - 2;
                const int glc = min(max(gl, 0), L_LEN - 1);
                if (IN0_F32) {
                    const float* s = (c < C0) ? (in0f + b * in0_b_stride + c * L_LEN)
                                              : nullptr;
                    v[u] = (c < C0) ? __float_as_uint(s[glc])
                                    : hprevp[(b * F_CH + (c - C0)) * L_LEN + glc];
                } else {
                    v[u] = (c < C0) ? in0p[(b * C0 + c) * L_LEN + glc]
                                    : hprevp[(b * F_CH + (c - C0)) * L_LEN + glc];
                }
            }
        }
        #pragma unroll
        for (int u = 0; u < U; ++u) {
            const int i = r * (512 * U) + u * 512 + tid;
            if (i < TOT) {
                const int c  = i / LP, lp = i - c * LP;
                const int gl = l0 + lp - 2;
                uint_t w = v[u];
                if (IN0_F32 && c < C0) w = pack_f32(__uint_as_float(w));
                if (gl < 0 || gl >= L_LEN) w = 0u;
                sh[lp * STRIDE + c] = w;
            }
        }
    }
    __syncthreads();

    const int w_id = tid >> 6;      // 0..7
    const int q    = w_id & 3;      // K-quarter
    const int nh   = w_id >> 2;     // N-half (columns nh*64 .. nh*64+63)
    const int lane = tid & 63;
    const int l16  = lane & 15, oct = lane >> 4;
    const int mrow = mblk * 64 + l16;
    const int k_lo = (q * KK) / 4, k_hi = ((q + 1) * KK) / 4;

    f32x4 acc[4][4];
    #pragma unroll
    for (int mt = 0; mt < 4; ++mt)
        #pragma unroll
        for (int nf = 0; nf < 4; ++nf) acc[mt][nf] = (f32x4)0.0f;

    const uint4* AH4 = (const uint4*)Ahi;
    const uint4* AL4 = (const uint4*)Alo;
    const uint4* shq = (const uint4*)sh;

    // 3-buffer A ring: loads issued 2 bodies ahead of consumption
    // (~930cy cover at 2 waves/SIMD > L3 latency).
    uint4 A0[8], A1[8], A2[8];
    auto loadA = [&](int kk, uint4* dst) {
        kk = min(kk, k_hi - 1);                  // clamped lookahead
        const int base = (kk * 4 + oct) * 512 + mrow;
        #pragma unroll
        for (int mt = 0; mt < 4; ++mt) {
            dst[2 * mt]     = AH4[base + 16 * mt];
            dst[2 * mt + 1] = AL4[base + 16 * mt];
        }
    };
    auto body = [&](int kk, uint4* A) {
        const int tap = kk / KS, ks = kk - tap * KS;
        const int cb  = ks * 8 + oct * 2;
        bf16x8 bh[4], bl[4];
        #pragma unroll
        for (int nf = 0; nf < 4; ++nf) {
            const int row = nh * 64 + nf * 16 + l16 + tap;
            const int r = row * (STRIDE / 4) + cb;
            uint4 p0 = shq[r], p1 = shq[r + 1];
            FragU H, L;
            H.q.x = __builtin_amdgcn_perm(p0.y, p0.x, 0x05040100u);
            H.q.y = __builtin_amdgcn_perm(p0.w, p0.z, 0x05040100u);
            H.q.z = __builtin_amdgcn_perm(p1.y, p1.x, 0x05040100u);
            H.q.w = __builtin_amdgcn_perm(p1.w, p1.z, 0x05040100u);
            L.q.x = __builtin_amdgcn_perm(p0.y, p0.x, 0x07060302u);
            L.q.y = __builtin_amdgcn_perm(p0.w, p0.z, 0x07060302u);
            L.q.z = __builtin_amdgcn_perm(p1.y, p1.x, 0x07060302u);
            L.q.w = __builtin_amdgcn_perm(p1.w, p1.z, 0x07060302u);
            bh[nf] = H.v; bl[nf] = L.v;
        }
        #pragma unroll
        for (int mt = 0; mt < 4; ++mt) {
            FragU TH, TL; TH.q = A[2 * mt]; TL.q = A[2 * mt + 1];
            bf16x8 ah = TH.v, al = TL.v;
            #pragma unroll
            for (int nf = 0; nf < 4; ++nf) {
                acc[mt][nf] = __builtin_amdgcn_mfma_f32_16x16x32_bf16(ah, bh[nf], acc[mt][nf], 0, 0, 0);
                acc[mt][nf] = __builtin_amdgcn_mfma_f32_16x16x32_bf16(al, bh[nf], acc[mt][nf], 0, 0, 0);
                acc[mt][nf] = __builtin_amdgcn_mfma_f32_16x16x32_bf16(ah, bl[nf], acc[mt][nf], 0, 0, 0);
            }
        }
    };

    // Prologue: 2 kk in flight; invariant at loop top: A0=kk, A1=kk+1.
    loadA(k_lo, A0);
    loadA(k_lo + 1, A1);
    int kk = k_lo;
    for (; kk + 3 <= k_hi; kk += 3) {
        loadA(kk + 2, A2); body(kk,     A0);
        loadA(kk + 3, A0); body(kk + 1, A1);
        loadA(kk + 4, A1); body(kk + 2, A2);
    }
    if (kk     < k_hi) body(kk,     A0);
    if (kk + 1 < k_hi) body(kk + 1, A1);

    // Cross-wave K-reduction through LDS (aliases staging tile).
    __syncthreads();
    float4* scratch = (float4*)sh;
    #pragma unroll
    for (int mt = 0; mt < 4; ++mt)
        #pragma unroll
        for (int nf = 0; nf < 4; ++nf) {
            FragU u; u.f = acc[mt][nf];
            scratch[(w_id * 16 + mt * 4 + nf) * 64 + lane] = u.f4;
        }
    __syncthreads();

    // Wave (q, nh) finalizes mtile q of N-half nh:
    // rows mblk*64+q*16..+15, columns l0+nh*64 .. +63.
    #pragma unroll
    for (int nf = 0; nf < 4; ++nf) {
        float4 s = scratch[((nh * 4 + 0) * 16 + q * 4 + nf) * 64 + lane];
        #pragma unroll
        for (int w = 1; w < 4; ++w) {
            float4 p = scratch[((nh * 4 + w) * 16 + q * 4 + nf) * 64 + lane];
            s.x += p.x; s.y += p.y; s.z += p.z; s.w += p.w;
        }
        const int rbase = mblk * 64 + q * 16 + 4 * oct;     // rows rbase..+3
        const float4 b4 = *(const float4*)(biasr + rbase);
        const int f = rbase >> 2;
        float gi = sigmoid_f(s.x + b4.x);
        float gf = sigmoid_f(s.y + b4.y);
        float go = sigmoid_f(s.z + b4.z);
        float gg = tanh_f(s.w + b4.w);
        const int l   = l0 + nh * 64 + nf * 16 + l16;
        const int idx = (b * F_CH + f) * L_LEN + l;
        float cp = c_in[idx];
        float cn = gf * cp + gi * gg;
        float hn = go * tanh_f(cn);
        c_out[idx] = cn;
        if (h_out_f32) h_out_f32[idx] = hn;
        hp_out[idx] = pack_f32(hn);
    }
}

// ---- Fused concurrent-pair kernel ----------------------------------------
// Launch t (t=0..T): bx<128 -> L1(t-1) [skip at t=0],
//                    bx>=128 -> L0(t)  [skip at t=T].
// Both halves depend only on launch-(t-1) outputs (t=0 state from prepass);
// kernel boundary is the sync + coherence point. 1 block/CU, grid 256.
struct FusedParams {
    const float* x;
    const ushort_t* Ahi0; const ushort_t* Alo0;
    const ushort_t* Ahi1; const ushort_t* Alo1;
    const float* br0; const float* br1;
    float* c0w; float* c1w;
    uint_t* hp0a; uint_t* hp0b;
    uint_t* hp1a; uint_t* hp1b;
    float* out;
};

__global__ __launch_bounds__(512)
void fused_step(FusedParams P, int t)
{
    constexpr int SH_WORDS = 132 * (256 + 4);    // 34320 w = 137.3 KB (>=RED 32768)
    __shared__ __align__(16) uint_t sh[SH_WORDS];

    const int tid  = threadIdx.x;
    const int bx   = blockIdx.x;
    const int mblk = bx & 7;                     // XCD-pinned (bx%8 round-robin)
    const int nblk = (bx & 127) >> 3;            // 0..15
    const int b    = nblk >> 1;
    const int l0   = (nblk & 1) << 7;

    if (bx < 128) {
        if (t >= 1) {
            const int tt = t - 1;
            const uint_t* hp0cur  = (tt & 1) ? P.hp0b : P.hp0a;  // L0(tt) output
            const uint_t* hp1prev = (tt & 1) ? P.hp1a : P.hp1b;
            uint_t*       hp1w    = (tt & 1) ? P.hp1b : P.hp1a;
            step_body<F_CH, 256, false>(sh, tid, mblk, b, l0,
                (const float*)nullptr, 0, hp0cur,
                hp1prev, P.Ahi1, P.Alo1, P.br1,
                P.c1w, P.c1w,
                P.out + (size_t)tt * S_BFL, hp1w);
        }
    } else {
        if (t < T_SZ) {
            const uint_t* hp0prev = (t & 1) ? P.hp0a : P.hp0b;
            uint_t*       hp0w    = (t & 1) ? P.hp0b : P.hp0a;
            step_body<CIN, 192, true>(sh, tid, mblk, b, l0,
                P.x + (size_t)t * CIN * L_LEN, T_SZ * CIN * L_LEN,
                (const uint_t*)nullptr,
                hp0prev, P.Ahi0, P.Alo0, P.br0,
                P.c0w, P.c0w,
                (float*)nullptr, hp0w);
        }
    }
}

extern "C" void kernel_launch(void* const* d_in, const int* in_sizes, int n_in,
                              void* d_out, int out_size, void* d_ws, size_t ws_size,
                              hipStream_t stream)
{
    const float* x  = (const float*)d_in[0];  // [B,T,Cin,L]
    const float* W0 = (const float*)d_in[1];  // [512,192,5]
    const float* b0 = (const float*)d_in[2];  // [512]
    const float* W1 = (const float*)d_in[3];  // [512,256,5]
    const float* b1 = (const float*)d_in[4];  // [512]
    const float* h0 = (const float*)d_in[5];  // [B,F,L]
    const float* c0 = (const float*)d_in[6];
    const float* h1 = (const float*)d_in[7];
    const float* c1 = (const float*)d_in[8];
    float* out = (float*)d_out;               // [T,B,F,L]

    const int S = S_BFL;
    float* ws  = (float*)d_ws;
    float* c0w = ws;                          // S floats
    float* c1w = ws + S;                      // S floats
    float* br0 = ws + 2 * S;                  // 512
    float* br1 = br0 + 512;
    uint_t* hp0a = (uint_t*)(ws + 2 * S + 1024);
    uint_t* hp0b = hp0a + S;
    uint_t* hp1a = hp0b + S;
    uint_t* hp1b = hp1a + S;
    ushort_t* Ahi0 = (ushort_t*)(hp1b + S);
    const int N0 = 512 * 192 * 5;             // 491520
    const int N1 = 512 * 256 * 5;             // 655360
    ushort_t* Alo0 = Ahi0 + N0;
    ushort_t* Ahi1 = Alo0 + N0;
    ushort_t* Alo1 = Ahi1 + N1;

    // Merged pre-pass (graph-safe, every call): weights, bias, and ALL
    // read-before-write workspace state in one launch.
    // Blocks: 240 convert_w<192> | 320 convert_w<256> | 4 bias | 1024 ws_init.
    prepass<<<dim3(240 + 320 + 4 + 1024), dim3(256), 0, stream>>>(
        W0, W1, b0, b1, h0, h1, c0, c1,
        Ahi0, Alo0, Ahi1, Alo1, br0, br1,
        hp0a, hp0b, hp1a, hp1b, c0w, c1w);

    FusedParams P;
    P.x = x;
    P.Ahi0 = Ahi0; P.Alo0 = Alo0; P.Ahi1 = Ahi1; P.Alo1 = Alo1;
    P.br0 = br0; P.br1 = br1;
    P.c0w = c0w; P.c1w = c1w;
    P.hp0a = hp0a; P.hp0b = hp0b; P.hp1a = hp1a; P.hp1b = hp1b;
    P.out = out;

    dim3 grid(256), block(512);
    for (int t = 0; t <= T_SZ; ++t) {
        fused_step<<<grid, block, 0, stream>>>(P, t);
    }
}